// Round 12
// baseline (572.251 us; speedup 1.0000x reference)
//
#include <hip/hip_runtime.h>
#include <math.h>

// VisualAttention, bf16x3 split-precision MFMA, distance-2 prefetch pipeline.
//   t = text@W + b; attn = softmax(obj@t^T); out = attn@t
// obj[8,1024,512] text[32768,768] W[768,512] b[512] -> out[8,1024,512] (fp32)
// fp32 x -> hi=bf16(x), lo=bf16(x-hi); A*B ~= Ah*Bh + Al*Bh + Ah*Bl (3 MFMAs).
// All GEMMs NT (B=[N,K], k contiguous). ws layout identical to round 3 (258MB, known-good).
//
// Round 12 = round 8-11 resubmit (broker timeouts; kernel unmeasured).
// Theory: k-step invariant ~3000cy = exposed global-load latency (53% of cycles
// neither MFMA nor VALU issue at 2 waves/SIMD -> counter-wait); distance-2
// prefetch gives each load ~2 k-steps in flight before its vmcnt-wait.

typedef unsigned short u16;
typedef u16   u16x4  __attribute__((ext_vector_type(4)));
typedef u16   u16x8  __attribute__((ext_vector_type(8)));
typedef __bf16 bf16x8 __attribute__((ext_vector_type(8)));
typedef float f32x4  __attribute__((ext_vector_type(4)));

// compiler-friendly split (emits v_cvt_pk_bf16_f32 pairs; m240: don't hand-roll)
__device__ inline void split4(const float4 v, u16x4* h4, u16x4* l4) {
  const float xs[4] = {v.x, v.y, v.z, v.w};
  #pragma unroll
  for (int c = 0; c < 4; c++) {
    __bf16 hb = (__bf16)xs[c];
    __bf16 lb = (__bf16)(xs[c] - (float)hb);
    (*h4)[c] = __builtin_bit_cast(u16, hb);
    (*l4)[c] = __builtin_bit_cast(u16, lb);
  }
}
__device__ inline u16x8 cat8(u16x4 a, u16x4 b) {
  u16x8 r;
  r[0]=a[0]; r[1]=a[1]; r[2]=a[2]; r[3]=a[3];
  r[4]=b[0]; r[5]=b[1]; r[6]=b[2]; r[7]=b[3];
  return r;
}

// ---------------- bf16x3 NT GEMM, dbuf LDS, distance-2 prefetch ----------------
// 128x128 tile, BK=32, 512 thr = 8 waves (2x4). LDS rows padded to 40 u16 (80B).
template<bool ADD_BIAS>
__global__ __launch_bounds__(512, 4) void gemm_nt_bf16x3(
    const float* __restrict__ A, const float* __restrict__ B,
    float* __restrict__ C, const float* __restrict__ bias,
    int M, int N, int K, long sA, long sB, long sC)
{
  __shared__ __align__(16) u16 Ah[2][128][40];
  __shared__ __align__(16) u16 Al[2][128][40];
  __shared__ __align__(16) u16 Bh[2][128][40];
  __shared__ __align__(16) u16 Bl[2][128][40];   // 80 KB -> 2 blocks/CU (LDS)

  const float* Ab = A + (long)blockIdx.z * sA;
  const float* Bb = B + (long)blockIdx.z * sB;
  float*       Cb = C + (long)blockIdx.z * sC;

  const int m0 = blockIdx.y * 128;
  const int n0 = blockIdx.x * 128;
  const int t    = threadIdx.x;
  const int lane = t & 63;
  const int w    = t >> 6;       // wave 0..7
  const int wm   = w >> 2;       // 2 wave-rows x 4 wave-cols; 64x32 out per wave
  const int wn   = w & 3;
  const int lr   = lane & 15;    // frag row/col  [m89/m91 layout]
  const int lg   = lane >> 4;    // k-group: k = lg*8 + j

  // staging: thread t owns row=t>>2 (0..127), kc=(t&3)*8 (8 contiguous k)
  const int srow = t >> 2;
  const int skc  = (t & 3) * 8;

  f32x4 acc[4][2];
  #pragma unroll
  for (int i = 0; i < 4; i++)
    #pragma unroll
    for (int j = 0; j < 2; j++) acc[i][j] = (f32x4){0.f, 0.f, 0.f, 0.f};

  // two named prefetch register sets (static indexing — rule #20)
  float4 aA0, aA1, bA0, bA1;   // set A
  float4 aB0, aB1, bB0, bB1;   // set B

  #define LOADK(A0, A1, B0, B1, K0)                                                  \
    {                                                                                 \
      const float* ap = Ab + (long)(m0 + srow) * K + (K0) + skc;                      \
      const float* bp = Bb + (long)(n0 + srow) * K + (K0) + skc;                      \
      A0 = *reinterpret_cast<const float4*>(ap);                                      \
      A1 = *reinterpret_cast<const float4*>(ap + 4);                                  \
      B0 = *reinterpret_cast<const float4*>(bp);                                      \
      B1 = *reinterpret_cast<const float4*>(bp + 4);                                  \
    }

  #define CONVWRITE(A0, A1, B0, B1, BUF)                                             \
    {                                                                                 \
      u16x4 h0, l0, h1, l1;                                                           \
      split4(A0, &h0, &l0); split4(A1, &h1, &l1);                                     \
      *reinterpret_cast<u16x8*>(&Ah[BUF][srow][skc]) = cat8(h0, h1);                  \
      *reinterpret_cast<u16x8*>(&Al[BUF][srow][skc]) = cat8(l0, l1);                  \
      split4(B0, &h0, &l0); split4(B1, &h1, &l1);                                     \
      *reinterpret_cast<u16x8*>(&Bh[BUF][srow][skc]) = cat8(h0, h1);                  \
      *reinterpret_cast<u16x8*>(&Bl[BUF][srow][skc]) = cat8(l0, l1);                  \
    }

  // fragments from buf CUR + 24 MFMA (term-outer: same-acc pairs 4 apart)
  #define COMPUTE(CUR)                                                               \
    {                                                                                 \
      bf16x8 afh[4], afl[4], bfh[2], bfl[2];                                          \
      _Pragma("unroll")                                                               \
      for (int i = 0; i < 4; i++) {                                                   \
        const int ar = wm * 64 + i * 16 + lr;                                         \
        afh[i] = __builtin_bit_cast(bf16x8, *reinterpret_cast<const u16x8*>(&Ah[CUR][ar][lg * 8])); \
        afl[i] = __builtin_bit_cast(bf16x8, *reinterpret_cast<const u16x8*>(&Al[CUR][ar][lg * 8])); \
      }                                                                               \
      _Pragma("unroll")                                                               \
      for (int j = 0; j < 2; j++) {                                                   \
        const int br = wn * 32 + j * 16 + lr;                                         \
        bfh[j] = __builtin_bit_cast(bf16x8, *reinterpret_cast<const u16x8*>(&Bh[CUR][br][lg * 8])); \
        bfl[j] = __builtin_bit_cast(bf16x8, *reinterpret_cast<const u16x8*>(&Bl[CUR][br][lg * 8])); \
      }                                                                               \
      _Pragma("unroll")                                                               \
      for (int j = 0; j < 2; j++) {                                                   \
        _Pragma("unroll")                                                             \
        for (int i = 0; i < 4; i++)                                                   \
          acc[i][j] = __builtin_amdgcn_mfma_f32_16x16x32_bf16(afl[i], bfh[j], acc[i][j], 0, 0, 0); \
        _Pragma("unroll")                                                             \
        for (int i = 0; i < 4; i++)                                                   \
          acc[i][j] = __builtin_amdgcn_mfma_f32_16x16x32_bf16(afh[i], bfl[j], acc[i][j], 0, 0, 0); \
        _Pragma("unroll")                                                             \
        for (int i = 0; i < 4; i++)                                                   \
          acc[i][j] = __builtin_amdgcn_mfma_f32_16x16x32_bf16(afh[i], bfh[j], acc[i][j], 0, 0, 0); \
      }                                                                               \
    }

  const int nk = K >> 5;   // 24 / 16 / 128 here — always even, >= 4

  // prologue: tile0 -> buf0 (one-time stall on its loads), then setA := tile1
  LOADK(aA0, aA1, bA0, bA1, 0)
  CONVWRITE(aA0, aA1, bA0, bA1, 0)
  LOADK(aA0, aA1, bA0, bA1, 32)
  __syncthreads();

  for (int kt = 0; kt < nk; kt += 2) {
    // even step: compute buf0, setA holds tile kt+1, load tile kt+2 into setB
    if (kt + 2 < nk) { LOADK(aB0, aB1, bB0, bB1, (kt + 2) << 5) }
    COMPUTE(0)
    CONVWRITE(aA0, aA1, bA0, bA1, 1)     // kt+1 <= nk-1 always (nk even)
    __syncthreads();
    // odd step: compute buf1, setB holds tile kt+2, load tile kt+3 into setA
    if (kt + 3 < nk) { LOADK(aA0, aA1, bA0, bA1, (kt + 3) << 5) }
    COMPUTE(1)
    if (kt + 2 < nk) { CONVWRITE(aB0, aB1, bB0, bB1, 0) }
    __syncthreads();
  }
  #undef LOADK
  #undef CONVWRITE
  #undef COMPUTE

  // epilogue: C/D frag col=lane&15, row=4*(lane>>4)+reg  [m89-verified]
  #pragma unroll
  for (int j = 0; j < 2; j++) {
    const int col = n0 + wn * 32 + j * 16 + lr;
    const float bj = ADD_BIAS ? bias[col] : 0.f;
    #pragma unroll
    for (int i = 0; i < 4; i++) {
      const int row = m0 + wm * 64 + i * 16 + lg * 4;
      #pragma unroll
      for (int r = 0; r < 4; r++)
        Cb[(long)(row + r) * N + col] = acc[i][j][r] + bj;
    }
  }
}

// ---------------- fp32 tiled transpose: out[C,R] = in[R,C]^T, batched ----------------
__global__ __launch_bounds__(256) void transpose_f32(
    const float* __restrict__ in, float* __restrict__ out,
    int R, int C, long sIn, long sOut)
{
  __shared__ float tile[32][33];
  in  += (long)blockIdx.z * sIn;
  out += (long)blockIdx.z * sOut;
  const int c  = blockIdx.x * 32 + threadIdx.x;
  const int r0 = blockIdx.y * 32 + threadIdx.y;
  #pragma unroll
  for (int j = 0; j < 32; j += 8)
    tile[threadIdx.y + j][threadIdx.x] = in[(long)(r0 + j) * C + c];
  __syncthreads();
  const int c2 = blockIdx.y * 32 + threadIdx.x;
  const int r2 = blockIdx.x * 32 + threadIdx.y;
  #pragma unroll
  for (int j = 0; j < 32; j += 8)
    out[(long)(r2 + j) * R + c2] = tile[threadIdx.x][threadIdx.y + j];
}

// ---------------- softmax over rows of 4096, in place ----------------
__device__ inline float wave_max(float x) {
  #pragma unroll
  for (int o = 1; o < 64; o <<= 1) x = fmaxf(x, __shfl_xor(x, o, 64));
  return x;
}
__device__ inline float wave_sum(float x) {
  #pragma unroll
  for (int o = 1; o < 64; o <<= 1) x += __shfl_xor(x, o, 64);
  return x;
}

__global__ __launch_bounds__(256) void softmax4096_kernel(float* __restrict__ attn)
{
  __shared__ float red[4];
  float* p = attn + (long)blockIdx.x * 4096;
  const int t = threadIdx.x;

  float4 v[4];
  float mx = -3.4e38f;
  #pragma unroll
  for (int i = 0; i < 4; i++) {
    v[i] = *reinterpret_cast<const float4*>(p + i * 1024 + t * 4);
    mx = fmaxf(mx, fmaxf(fmaxf(v[i].x, v[i].y), fmaxf(v[i].z, v[i].w)));
  }
  mx = wave_max(mx);
  if ((t & 63) == 0) red[t >> 6] = mx;
  __syncthreads();
  mx = fmaxf(fmaxf(red[0], red[1]), fmaxf(red[2], red[3]));
  __syncthreads();

  float s = 0.f;
  #pragma unroll
  for (int i = 0; i < 4; i++) {
    v[i].x = __expf(v[i].x - mx); s += v[i].x;
    v[i].y = __expf(v[i].y - mx); s += v[i].y;
    v[i].z = __expf(v[i].z - mx); s += v[i].z;
    v[i].w = __expf(v[i].w - mx); s += v[i].w;
  }
  s = wave_sum(s);
  if ((t & 63) == 0) red[t >> 6] = s;
  __syncthreads();
  const float r = 1.f / (red[0] + red[1] + red[2] + red[3]);

  #pragma unroll
  for (int i = 0; i < 4; i++) {
    v[i].x *= r; v[i].y *= r; v[i].z *= r; v[i].w *= r;
    *reinterpret_cast<float4*>(p + i * 1024 + t * 4) = v[i];
  }
}

extern "C" void kernel_launch(void* const* d_in, const int* in_sizes, int n_in,
                              void* d_out, int out_size, void* d_ws, size_t ws_size,
                              hipStream_t stream)
{
  const float* obj  = (const float*)d_in[0];  // [8,1024,512]
  const float* text = (const float*)d_in[1];  // [32768,768]
  const float* W    = (const float*)d_in[2];  // [768,512]
  const float* bias = (const float*)d_in[3];  // [512]
  float*       out  = (float*)d_out;          // [8,1024,512]

  // ws: t[32768,512] | attn[8,1024,4096] | tT[8,512,4096] | WT[512,768]  (~258 MB, known-good)
  float* t    = (float*)d_ws;
  float* attn = t    + 32768L * 512;
  float* tT   = attn + 8L * 1024 * 4096;
  float* WT   = tT   + 8L * 512 * 4096;

  // T0: WT = W^T
  transpose_f32<<<dim3(512 / 32, 768 / 32, 1), dim3(32, 8), 0, stream>>>(
      W, WT, 768, 512, 0L, 0L);
  // K1: t = text @ WT^T + bias    M=32768 N=512 K=768
  gemm_nt_bf16x3<true><<<dim3(512 / 128, 32768 / 128, 1), 512, 0, stream>>>(
      text, WT, t, bias, 32768, 512, 768, 0L, 0L, 0L);
  // T1: tT[b] = t[b]^T
  transpose_f32<<<dim3(512 / 32, 4096 / 32, 8), dim3(32, 8), 0, stream>>>(
      t, tT, 4096, 512, 4096L * 512, 512L * 4096);
  // K2: attn = obj @ t^T (per batch)   M=1024 N=4096 K=512
  gemm_nt_bf16x3<false><<<dim3(4096 / 128, 1024 / 128, 8), 512, 0, stream>>>(
      obj, t, attn, nullptr, 1024, 4096, 512,
      1024L * 512, 4096L * 512, 1024L * 4096);
  // K3: row softmax, 8192 rows of 4096
  softmax4096_kernel<<<8192, 256, 0, stream>>>(attn);
  // K4: out = attn @ tT^T (per batch)  M=1024 N=512 K=4096
  gemm_nt_bf16x3<false><<<dim3(512 / 128, 1024 / 128, 8), 512, 0, stream>>>(
      attn, tT, out, nullptr, 1024, 512, 4096,
      1024L * 4096, 512L * 4096, 1024L * 512);
}